// Round 8
// baseline (784602.490 us; speedup 1.0000x reference)
//
#include <hip/hip_runtime.h>
#include <stdint.h>

// RNNPPO: LSTM(512 steps) + ragged pack + 2x MLP heads. DTYPE-ROBUST (sniff
// fp32-vs-bf16, normalize to bf16, output per mode).
//
// R15 (lstm sync): R13/R14 (pure tag-fused sc0 poll) died twice with no
// harness data -- cause unprovable (infra vs systematic poll-wedge timeout).
// R15 = R12's PROVEN skeleton (1940us, sc0 scope verified by preflight
// probe) + the tag-fused shortcut as a bounded OPPORTUNISTIC path:
//  - hbuf = tagged u64 {tag32, 2xbf16}; producer payload stores sc0,
//    ack-free at epilogue.
//  - producer's vmcnt(0)+barrier+tag release moved to TOP of next iter
//    (off the inter-WG chain; runs concurrent with consumers).
//  - consumer: 6-round quick poll (poll IS the data: 4x dwordx4 sc0,
//    8 embedded tags). Hit => skip ack/tag-flight/detect legs entirely.
//    Miss => R12's proven sc0 tag-line detect + one reload. SAME scope.
//  - probe-fail => full agent protocol from R10/R11-proven constructs.
// Every wait is bounded; worst case ~= R12 + 6 cheap rounds/step.

#define T_STEPS 512
#define BATCH   128
#define DDIM    256
#define HDIM    512

typedef __attribute__((ext_vector_type(8))) short bf16x8;
typedef __attribute__((ext_vector_type(4))) float f32x4;
typedef __attribute__((ext_vector_type(2))) unsigned long long u64x2;
typedef unsigned short u16;
typedef unsigned int   u32;
typedef unsigned long long u64;
typedef __attribute__((ext_vector_type(4))) u32 u32x4;
typedef __attribute__((ext_vector_type(2))) u32 u32x2;

__device__ __forceinline__ u16 f2bf(float x){
  u32 u = __builtin_bit_cast(u32, x);
  u32 r = u + 0x7fffu + ((u >> 16) & 1u);
  return (u16)(r >> 16);
}
__device__ __forceinline__ float bf2f(u16 h){
  u32 u = ((u32)h) << 16;
  return __builtin_bit_cast(float, u);
}
__device__ __forceinline__ float sigm(float x){ return 1.f/(1.f + __expf(-x)); }
__device__ __forceinline__ float tanh_f(float x){ return 1.f - 2.f/(1.f + __expf(2.f*x)); }

__device__ __forceinline__ void async_ld16(const void* g, void* l){
  __builtin_amdgcn_global_load_lds(
      (const __attribute__((address_space(1))) u32*)g,
      (__attribute__((address_space(3))) u32*)l, 16, 0, 0);
}

// ---- SE(XCD-L2)-scope ops: sc0 = bypass L1, service at this XCD's L2 ----
__device__ __forceinline__ u32 ld_u32_sc0(const int* p){
  u32 v;
  asm volatile("global_load_dword %0, %1, off sc0\n\t"
               "s_waitcnt vmcnt(0)"
               : "=&v"(v) : "v"(p) : "memory");
  return v;
}
__device__ __forceinline__ void st_u32_sc0(int* p, u32 v){
  asm volatile("global_store_dword %0, %1, off sc0" :: "v"(p), "v"(v) : "memory");
}
__device__ __forceinline__ void st_u32x2_sc0(void* p, u32x2 v){
  asm volatile("global_store_dwordx2 %0, %1, off sc0" :: "v"(p), "v"(v) : "memory");
}
// 4x 16B sc0 loads, completed before return (quick poll: poll IS the data)
__device__ __forceinline__ void ld4_b128_sc0(const void* p0, const void* p1,
                                             const void* p2, const void* p3,
                                             u32x4& A0, u32x4& A1,
                                             u32x4& A2, u32x4& A3){
  asm volatile("global_load_dwordx4 %0, %4, off sc0\n\t"
               "global_load_dwordx4 %1, %5, off sc0\n\t"
               "global_load_dwordx4 %2, %6, off sc0\n\t"
               "global_load_dwordx4 %3, %7, off sc0\n\t"
               "s_waitcnt vmcnt(0)"
               : "=&v"(A0), "=&v"(A1), "=&v"(A2), "=&v"(A3)
               : "v"(p0), "v"(p1), "v"(p2), "v"(p3)
               : "memory");
}
// system-scope variant (agent fallback data load; R10-proven construct)
__device__ __forceinline__ void ld4_b128_cc(const void* p0, const void* p1,
                                            const void* p2, const void* p3,
                                            u32x4& A0, u32x4& A1,
                                            u32x4& A2, u32x4& A3){
  asm volatile("global_load_dwordx4 %0, %4, off sc0 sc1\n\t"
               "global_load_dwordx4 %1, %5, off sc0 sc1\n\t"
               "global_load_dwordx4 %2, %6, off sc0 sc1\n\t"
               "global_load_dwordx4 %3, %7, off sc0 sc1\n\t"
               "s_waitcnt vmcnt(0)"
               : "=&v"(A0), "=&v"(A1), "=&v"(A2), "=&v"(A3)
               : "v"(p0), "v"(p1), "v"(p2), "v"(p3)
               : "memory");
}

// ---------------- dtype sniff ----------------
__global__ void sniff_kernel(const u16* __restrict__ b, int* __restrict__ mode){
  if (threadIdx.x == 0){
    int bad = 0;
    for (int i = 0; i < 64; i++){
      u16 x = b[2*i];
      int e = (x >> 7) & 0xFF;         // bf16 exponent
      if (e < 0x60 || e > 0x85) bad++; // outside ~[2^-31, 2^6]
    }
    *mode = (bad > 16) ? 1 : 0;        // 1 = fp32 inputs, 0 = bf16 inputs
  }
}

// ---------------- convert anything -> bf16 ----------------
__global__ void cvt_kernel(const void* __restrict__ src, u16* __restrict__ dst,
                           int n, const int* __restrict__ mode){
  int i0 = (blockIdx.x*blockDim.x + threadIdx.x) * 8;
  if (i0 >= n) return;
  int m = *mode;
  if (m){
    const float* s = (const float*)src;
    if (i0 + 8 <= n){
      float4 a = *(const float4*)(s + i0);
      float4 b = *(const float4*)(s + i0 + 4);
      ushort4 oa, ob;
      oa.x=f2bf(a.x); oa.y=f2bf(a.y); oa.z=f2bf(a.z); oa.w=f2bf(a.w);
      ob.x=f2bf(b.x); ob.y=f2bf(b.y); ob.z=f2bf(b.z); ob.w=f2bf(b.w);
      *(ushort4*)(dst + i0) = oa;
      *(ushort4*)(dst + i0 + 4) = ob;
    } else {
      for (int i = i0; i < n; i++) dst[i] = f2bf(s[i]);
    }
  } else {
    const u16* s = (const u16*)src;
    if (i0 + 8 <= n){
      *(ushort4*)(dst + i0)     = *(const ushort4*)(s + i0);
      *(ushort4*)(dst + i0 + 4) = *(const ushort4*)(s + i0 + 4);
    } else {
      for (int i = i0; i < n; i++) dst[i] = s[i];
    }
  }
}

// ---------------- tagged h_{-1} init ----------------
// hbuf: [2 parities][BATCH*HDIM/2] u64 {hi32 = step tag, lo32 = 2 bf16}.
// Parity 1 = h_{-1} tag 0 (t=0 wants >=0); parity 0 tag 0 (t=1 wants >=1).
__global__ void init_h_kernel(const void* __restrict__ h0,
                              u64* __restrict__ hbuf,
                              const int* __restrict__ mode){
  int i = blockIdx.x*blockDim.x + threadIdx.x;
  if (i >= BATCH*HDIM/2) return;
  u16 a, b;
  if (*mode){
    const float* s = (const float*)h0;
    a = f2bf(s[2*i]); b = f2bf(s[2*i + 1]);
  } else {
    const u16* s = (const u16*)h0;
    a = s[2*i]; b = s[2*i + 1];
  }
  hbuf[i] = 0ull;                                        // parity 0: tag 0
  hbuf[BATCH*HDIM/2 + i] = (u64)a | ((u64)b << 16);      // parity 1: h_{-1}
}

// ---------------- prep ----------------
__global__ void scan_kernel(const int* __restrict__ lens, int* __restrict__ off){
  if (threadIdx.x == 0){
    int a = 0;
    for (int b = 0; b < BATCH; b++){ off[b] = a; a += lens[b]; }
    off[BATCH] = a;
  }
}

__global__ void pack_state_kernel(const u16* __restrict__ st_bf,
                                  const int* __restrict__ lens,
                                  const int* __restrict__ off,
                                  u16* __restrict__ inp){
  int r = blockIdx.x*4 + (threadIdx.x >> 6);   // dense row t*BATCH+b
  int lane = threadIdx.x & 63;
  int b = r & (BATCH-1), t = r >> 7;
  if (t >= lens[b]) return;
  long row = (long)off[b] + t;
  ushort4 v = ((const ushort4*)(st_bf + (long)r*DDIM))[lane];
  ((ushort4*)(inp + row*768))[lane] = v;
}

__global__ void zero_out_kernel(void* __restrict__ out, int n,
                                const int* __restrict__ mode){
  int i = blockIdx.x*blockDim.x + threadIdx.x;
  if (i >= n) return;
  if (*mode) ((float*)out)[i] = 0.f; else ((u16*)out)[i] = 0;
}

// ---------------- LSTM recurrence ----------------
__global__ __launch_bounds__(512, 1) void lstm_kernel(
    const u16* __restrict__ Whh, const u16* __restrict__ Wih,
    const u16* __restrict__ bih, const u16* __restrict__ bhh,
    const u16* __restrict__ cell0,
    const u16* __restrict__ state,
    u64* hbuf,                              // [2][BATCH*HDIM/2] tagged pairs
    u16* __restrict__ inp,                  // [Np128*768]
    const int* __restrict__ off, const int* __restrict__ lens,
    int* tags,                              // [8*16] backstop per-(g,s) tags
    int* probe)                             // [128 sig][128 ptag][bad][cnt]
{
  const int tid  = threadIdx.x;
  const int wave = tid >> 6;
  const int lane = tid & 63;
  const int g    = blockIdx.x & 7;      // batch group == XCD (round-robin)
  const int s    = blockIdx.x >> 3;     // col-WG 0..15 (32 h-cols each)
  const int Sb   = s * 32;
  const int q    = lane >> 4;
  const int m16  = lane & 15;
  const int HP   = HDIM / 2;            // 256 u64 pairs per h row

  __shared__ u16  wlds[65536];          // 128 KB
  __shared__ u16  hlds[8192];           // 16 KB
  __shared__ float lds_acc[8][16][16];  // 8 KB
  __shared__ float bias_l[128];
  __shared__ int   len_l[16];
  __shared__ int   off_l[16];
  __shared__ int   fast_l;

  // -------- preflight: sc0 same-XCD visibility probe + global consensus ---
  // (verbatim R12 -- ran and engaged correctly at 1940us)
  if (wave == 0){
    if (lane == 0){
      st_u32_sc0(&probe[blockIdx.x], 0xC0FFEE00u | (u32)blockIdx.x);
      asm volatile("s_waitcnt vmcnt(0)" ::: "memory");
      st_u32_sc0(&probe[128 + blockIdx.x], 1u);
    }
    int seen = 1;
    if (lane < 16){
      int partner = 8*lane + g;         // the 16 WGs of group g
      seen = 0;
      for (int sp = 0; sp < (1 << 11); sp++){
        u32 tgv = ld_u32_sc0(&probe[128 + partner]);
        if (tgv == 1u){
          u32 v = ld_u32_sc0(&probe[partner]);
          if (v == (0xC0FFEE00u | (u32)partner)) seen = 1;
          break;                        // tag seen: sig must match NOW
        }
      }
    }
    int okl = __all(seen != 0) ? 1 : 0;
    if (lane == 0){
      if (!okl)
        __hip_atomic_fetch_or(&probe[256], 1,
                              __ATOMIC_RELAXED, __HIP_MEMORY_SCOPE_AGENT);
      __hip_atomic_fetch_add(&probe[257], 1,
                             __ATOMIC_RELEASE, __HIP_MEMORY_SCOPE_AGENT);
      int sp2 = 0;
      while (__hip_atomic_load(&probe[257], __ATOMIC_ACQUIRE,
                               __HIP_MEMORY_SCOPE_AGENT) < 128){
        if (++sp2 >= (1 << 16)) break;
      }
      int bad = __hip_atomic_load(&probe[256], __ATOMIC_RELAXED,
                                  __HIP_MEMORY_SCOPE_AGENT);
      int cnt = __hip_atomic_load(&probe[257], __ATOMIC_RELAXED,
                                  __HIP_MEMORY_SCOPE_AGENT);
      if (sp2 >= (1 << 16)) bad = 1;
      fast_l = (!bad && cnt >= 128) ? 1 : 0;
    }
  }

  if (tid < 128){
    int gt = tid >> 5, jx = tid & 31;
    int cg = gt*HDIM + Sb + jx;
    bias_l[tid] = bf2f(bih[cg]) + bf2f(bhh[cg]);
  }
  if (tid < 16){ len_l[tid] = lens[g*16 + tid]; off_l[tid] = off[g*16 + tid]; }

  // one-time: stage Whh slice into LDS, frag order:
  // chunk ch = (w*16 + c)*64 + l  holds  W[col(w, l&15)][c*32 + (l>>4)*8 ..+8]
  for (int i = 0; i < 16; i++){
    int ch = tid + 512*i;               // 0..8191
    int w = ch >> 10;
    int rem = ch & 1023;
    int c = rem >> 6;
    int l = rem & 63;
    int col = (w >> 1)*HDIM + Sb + (w & 1)*16 + (l & 15);
    int k = c*32 + (l >> 4)*8;
    u64x2 v = *(const u64x2*)(Whh + (long)col*HDIM + k);
    *(u64x2*)(&wlds[(size_t)ch*8]) = v;
  }

  // Wih fragments in VGPRs
  const int gate = wave >> 1;
  const int hf   = wave & 1;
  const int colg = gate*HDIM + Sb + hf*16 + m16;
  bf16x8 wih[8];
  {
    const u16* wb2 = Wih + (long)colg*DDIM + q*8;
    #pragma unroll
    for (int c = 0; c < 8; c++) wih[c] = *(const bf16x8*)(wb2 + c*32);
  }

  const int b_l = tid >> 5;    // epilogue ownership: (batch b_l, col j)
  const int j   = tid & 31;
  const int hx  = j >> 4;
  const int jj  = j & 15;
  float cval = bf2f(cell0[(g*16 + b_l)*HDIM + Sb + j]);

  // consumer co-op chunk assignment (2 chunks/thread, conflict-free writes)
  const int m0 = tid, m1 = tid + 512;
  const int c0i = m0 >> 6, c1i = m1 >> 6;
  const int r0 = m0 & 15;                 // == m1 & 15
  const int k0 = c0i*32 + ((m0 & 63) >> 4)*8;
  const int k1 = c1i*32 + ((m1 & 63) >> 4)*8;
  const int p0i = r0*HP + (k0 >> 1);      // first of 4 contiguous u64
  const int p1i = r0*HP + (k1 >> 1);

  int* tg = tags + g*16;

  __syncthreads();
  const int fast = fast_l;

  for (int t = 0; t < T_STEPS; t++){
    // R: release block for step t-1's stores (producer-side, OFF the
    // inter-WG chain: consumers usually validate from the data itself).
    if (t > 0){
      __builtin_amdgcn_s_waitcnt(0);   // own h payload (+inp) stores done
      __syncthreads();                 // all waves acked
      if (tid == 0){
        if (fast) st_u32_sc0(&tg[s], (u32)t);
        else      __hip_atomic_store(&tg[s], t,
                                     __ATOMIC_RELAXED, __HIP_MEMORY_SCOPE_AGENT);
      }
    }
    f32x4 acc  = {0.f, 0.f, 0.f, 0.f};
    f32x4 acc2 = {0.f, 0.f, 0.f, 0.f};
    // B: h gather. Fast: 6-round quick poll (poll IS the data), backstop =
    // R12 tag-line detect + one reload. Slow: agent detect + reload.
    const u64* hp = hbuf + (size_t)((t & 1) ^ 1)*(BATCH*HP) + (size_t)g*16*HP;
    const u64* c0p = hp + p0i;
    const u64* c1p = hp + p1i;
    const u32 want = (u32)t;
    u32x4 A0, A1, A2, A3;
    if (fast){
      bool valid = false;
      #pragma unroll 1
      for (int r = 0; r < 6; r++){
        ld4_b128_sc0(c0p, c0p + 2, c1p, c1p + 2, A0, A1, A2, A3);
        if (A0[1] >= want && A0[3] >= want && A1[1] >= want && A1[3] >= want &&
            A2[1] >= want && A2[3] >= want && A3[1] >= want && A3[3] >= want){
          valid = true; break;
        }
      }
      if (!valid){
        // backstop: R12-proven sc0 tag-line detect, then one reload
        int spins = 0;
        for (;;){
          int tv = 0x7fffffff;
          if (lane < 16) tv = (int)ld_u32_sc0(&tg[lane]);
          if (__all(tv >= (int)want)) break;
          if (++spins > (1 << 14)) break;  // wedge -> wrong answer, not hang
        }
        asm volatile("" ::: "memory");
        ld4_b128_sc0(c0p, c0p + 2, c1p, c1p + 2, A0, A1, A2, A3);
      }
    } else {
      // agent path: R11-proven detect + R10-proven wide load
      if (t > 0){
        int spins = 0;
        for (;;){
          int tv = 0x7fffffff;
          if (lane < 16)
            tv = __hip_atomic_load(&tg[lane], __ATOMIC_RELAXED,
                                   __HIP_MEMORY_SCOPE_AGENT);
          if (__all(tv >= (int)want)) break;
          if (++spins > (1 << 14)) break;
        }
        asm volatile("" ::: "memory");
      }
      ld4_b128_cc(c0p, c0p + 2, c1p, c1p + 2, A0, A1, A2, A3);
    }
    // C: x loads (plain cached; co-XCD group -> L2-hit after 1st WG)
    bf16x8 xa[8];
    {
      const u16* xb = state + ((long)(t*BATCH + g*16 + m16))*DDIM + q*8;
      #pragma unroll
      for (int c = 0; c < 8; c++) xa[c] = *(const bf16x8*)(xb + c*32);
    }
    // D: h tile -> LDS from payload lo32 words
    {
      u32x4 v; v[0] = A0[0]; v[1] = A0[2]; v[2] = A1[0]; v[3] = A1[2];
      *(u32x4*)(&hlds[(size_t)m0*8]) = v;
    }
    {
      u32x4 v; v[0] = A2[0]; v[1] = A2[2]; v[2] = A3[0]; v[3] = A3[2];
      *(u32x4*)(&hlds[(size_t)m1*8]) = v;
    }
    // E: x MFMAs (overlap x-load completion with other waves' LDS writes)
    #pragma unroll
    for (int c = 0; c < 8; c++)
      acc = __builtin_amdgcn_mfma_f32_16x16x32_bf16(xa[c], wih[c], acc, 0, 0, 0);
    __syncthreads();                   // barrier 1: hlds ready
    // F: h MFMAs, weights from LDS (two interleaved chains; R12-proven)
    #pragma unroll
    for (int cc = 0; cc < 8; cc++){
      bf16x8 a0 = *(const bf16x8*)(&hlds[(size_t)((2*cc    )*64 + lane)*8]);
      bf16x8 a1 = *(const bf16x8*)(&hlds[(size_t)((2*cc + 1)*64 + lane)*8]);
      bf16x8 w0 = *(const bf16x8*)(&wlds[(size_t)((wave*16 + 2*cc    )*64 + lane)*8]);
      bf16x8 w1 = *(const bf16x8*)(&wlds[(size_t)((wave*16 + 2*cc + 1)*64 + lane)*8]);
      acc  = __builtin_amdgcn_mfma_f32_16x16x32_bf16(a0, w0, acc,  0, 0, 0);
      acc2 = __builtin_amdgcn_mfma_f32_16x16x32_bf16(a1, w1, acc2, 0, 0, 0);
    }
    // G: gate exchange through LDS (C layout: row(batch)=q*4+r, col=m16)
    #pragma unroll
    for (int r = 0; r < 4; r++)
      lds_acc[wave][q*4 + r][m16] = acc[r] + acc2[r];
    __syncthreads();                   // barrier 2: gates ready

    // H: epilogue + ack-free tagged payload stores
    float iv = lds_acc[0 + hx][b_l][jj] + bias_l[ 0 + j];
    float fv = lds_acc[2 + hx][b_l][jj] + bias_l[32 + j];
    float gv = lds_acc[4 + hx][b_l][jj] + bias_l[64 + j];
    float ov = lds_acc[6 + hx][b_l][jj] + bias_l[96 + j];
    cval = sigm(fv)*cval + sigm(iv)*tanh_f(gv);
    float hvf = sigm(ov)*tanh_f(cval);
    u16 hb16 = f2bf(hvf);
    int nb = __shfl_down((int)hb16, 1);
    if ((j & 1) == 0){
      size_t hidx = (size_t)(t & 1)*(BATCH*HP) + (size_t)(g*16 + b_l)*HP
                  + (size_t)((Sb + j) >> 1);
      u32 lo = (u32)hb16 | ((u32)(u16)nb << 16);
      if (fast){
        u32x2 pv; pv[0] = lo; pv[1] = (u32)(t + 1);
        st_u32x2_sc0(hbuf + hidx, pv);
      } else {
        u64 payload = (u64)lo | ((u64)(u32)(t + 1) << 32);
        __hip_atomic_store(hbuf + hidx, payload,
                           __ATOMIC_RELAXED, __HIP_MEMORY_SCOPE_AGENT);
      }
    }
    // packed-h store fully off the release path
    if (t < len_l[b_l])
      inp[((long)(off_l[b_l] + t))*768 + DDIM + Sb + j] = hb16;
  }
}

// ---------------- MLP GEMM: C = relu(A @ W^T + bias), bf16 in/out ----------------
__global__ __launch_bounds__(256) void gemm_kernel(
    const u16* __restrict__ A,   // [rows x K]
    const u16* __restrict__ W,   // [512 x K]
    const u16* __restrict__ bias,
    u16* __restrict__ C,         // [rows x 512]
    int K)
{
  __shared__ u16 As[128*32];
  __shared__ u16 Bs[128*32];
  const int tid = threadIdx.x, wave = tid >> 6, lane = tid & 63;
  const int bm = blockIdx.x * 128;
  const int bn = blockIdx.y * 128;
  const int wr = (wave >> 1) * 64;
  const int wc = (wave & 1) * 64;
  const int q = lane >> 4, m16 = lane & 15;
  const int rsub = lane >> 2;          // 0..15
  const int ksub = (lane & 3) * 8;     // elems

  f32x4 acc[4][4] = {};

  for (int k0 = 0; k0 < K; k0 += 32){
    __syncthreads();
    #pragma unroll
    for (int i = 0; i < 2; i++){
      int rr = (i*4 + wave) * 16 + rsub;
      async_ld16(A + (long)(bm + rr)*K + k0 + ksub, As + (i*4 + wave)*512);
      async_ld16(W + (long)(bn + rr)*K + k0 + ksub, Bs + (i*4 + wave)*512);
    }
    __syncthreads();
    bf16x8 af[4], bfr[4];
    #pragma unroll
    for (int r = 0; r < 4; r++) af[r]  = *(const bf16x8*)(As + (wr + r*16 + m16)*32 + q*8);
    #pragma unroll
    for (int c = 0; c < 4; c++) bfr[c] = *(const bf16x8*)(Bs + (wc + c*16 + m16)*32 + q*8);
    #pragma unroll
    for (int r = 0; r < 4; r++)
      #pragma unroll
      for (int c = 0; c < 4; c++)
        acc[r][c] = __builtin_amdgcn_mfma_f32_16x16x32_bf16(af[r], bfr[c], acc[r][c], 0, 0, 0);
  }
  #pragma unroll
  for (int c = 0; c < 4; c++){
    int col = bn + wc + c*16 + m16;
    float bv = bf2f(bias[col]);
    #pragma unroll
    for (int r = 0; r < 4; r++){
      #pragma unroll
      for (int x = 0; x < 4; x++){
        int row = bm + wr + r*16 + q*4 + x;
        float v = acc[r][c][x] + bv;
        v = fmaxf(v, 0.f);
        C[(long)row*512 + col] = f2bf(v);
      }
    }
  }
}

// ---------------- final fused layer: actor(3, tanh) + critic(1) ----------------
__global__ void final_kernel(
    const u16* __restrict__ a2, const u16* __restrict__ c2,
    const u16* __restrict__ aw2, const u16* __restrict__ ab2,
    const u16* __restrict__ cw2, const u16* __restrict__ cb2,
    void* __restrict__ out, int base, int nvalid, int N,
    const int* __restrict__ mode)
{
  int lw = (blockIdx.x * blockDim.x + threadIdx.x) >> 6;   // local row
  int lane = threadIdx.x & 63;
  if (lw >= nvalid) return;
  int k = lane * 8;
  bf16x8 av = *(const bf16x8*)(a2 + (long)lw*512 + k);
  bf16x8 cv = *(const bf16x8*)(c2 + (long)lw*512 + k);
  bf16x8 w0 = *(const bf16x8*)(aw2 + k);
  bf16x8 w1 = *(const bf16x8*)(aw2 + 512 + k);
  bf16x8 w2 = *(const bf16x8*)(aw2 + 1024 + k);
  bf16x8 wc = *(const bf16x8*)(cw2 + k);
  float d0=0.f, d1=0.f, d2=0.f, dc=0.f;
  #pragma unroll
  for (int x = 0; x < 8; x++){
    float a  = bf2f((u16)av[x]);
    float cc = bf2f((u16)cv[x]);
    d0 += a  * bf2f((u16)w0[x]);
    d1 += a  * bf2f((u16)w1[x]);
    d2 += a  * bf2f((u16)w2[x]);
    dc += cc * bf2f((u16)wc[x]);
  }
  #pragma unroll
  for (int o = 32; o > 0; o >>= 1){
    d0 += __shfl_down(d0, o);
    d1 += __shfl_down(d1, o);
    d2 += __shfl_down(d2, o);
    dc += __shfl_down(dc, o);
  }
  if (lane == 0){
    int gr = base + lw;
    float r0 = tanh_f(d0 + bf2f(ab2[0]));
    float r1 = tanh_f(d1 + bf2f(ab2[1]));
    float r2 = tanh_f(d2 + bf2f(ab2[2]));
    float rc = dc + bf2f(cb2[0]);
    if (*mode){
      float* o = (float*)out;
      o[(long)gr*3 + 0] = r0; o[(long)gr*3 + 1] = r1; o[(long)gr*3 + 2] = r2;
      o[(long)3*N + gr] = rc;
    } else {
      u16* o = (u16*)out;
      o[(long)gr*3 + 0] = f2bf(r0); o[(long)gr*3 + 1] = f2bf(r1);
      o[(long)gr*3 + 2] = f2bf(r2);
      o[(long)3*N + gr] = f2bf(rc);
    }
  }
}

extern "C" void kernel_launch(void* const* d_in, const int* in_sizes, int n_in,
                              void* d_out, int out_size, void* d_ws, size_t ws_size,
                              hipStream_t stream)
{
  const void* state = d_in[0];
  const void* h0    = d_in[1];
  const void* c0    = d_in[2];
  const int*  lens  = (const int*)d_in[3];
  const void* Wih   = d_in[4];
  const void* Whh   = d_in[5];
  const void* bih   = d_in[6];
  const void* bhh   = d_in[7];
  const void* aw0   = d_in[8];
  const void* ab0   = d_in[9];
  const void* aw1   = d_in[10];
  const void* ab1   = d_in[11];
  const void* aw2   = d_in[12];
  const void* ab2   = d_in[13];
  const void* cw0   = d_in[14];
  const void* cb0   = d_in[15];
  const void* cw1   = d_in[16];
  const void* cb1   = d_in[17];
  const void* cw2   = d_in[18];
  const void* cb2   = d_in[19];
  (void)in_sizes; (void)n_in;

  const int N = out_size / 4;             // actor 3N + critic N
  const int Np128 = (N + 127) & ~127;

  char* ws = (char*)d_ws;
  size_t cur = 0;
  auto alloc = [&](size_t bytes)->char*{
    char* p = ws + cur; cur += (bytes + 255) & ~(size_t)255; return p;
  };
  int* mode   = (int*)alloc(4);
  int* off    = (int*)alloc(129*4);
  int* tags   = (int*)alloc(128*4);
  int* probe  = (int*)alloc(512*4);
  u64* hbuf   = (u64*)alloc((size_t)2*(BATCH*HDIM/2)*8);   // tagged pairs
  u16* cbf    = (u16*)alloc((size_t)BATCH*HDIM*2);
  u16* wih_b  = (u16*)alloc((size_t)2048*256*2);
  u16* whh_b  = (u16*)alloc((size_t)2048*512*2);
  u16* bih_b  = (u16*)alloc(2048*2);
  u16* bhh_b  = (u16*)alloc(2048*2);
  u16* st_bf  = (u16*)alloc((size_t)T_STEPS*BATCH*DDIM*2);
  u16* wa0    = (u16*)alloc((size_t)512*768*2);
  u16* ba0    = (u16*)alloc(512*2);
  u16* wa1    = (u16*)alloc((size_t)512*512*2);
  u16* ba1    = (u16*)alloc(512*2);
  u16* wa2    = (u16*)alloc(1536*2);
  u16* ba2    = (u16*)alloc(256*2);
  u16* wc0    = (u16*)alloc((size_t)512*768*2);
  u16* bc0    = (u16*)alloc(512*2);
  u16* wc1    = (u16*)alloc((size_t)512*512*2);
  u16* bc1    = (u16*)alloc(512*2);
  u16* wc2    = (u16*)alloc(512*2);
  u16* bc2    = (u16*)alloc(256*2);
  u16* inp    = (u16*)alloc((size_t)Np128*768*2);

  sniff_kernel<<<1, 64, 0, stream>>>((const u16*)bih, mode);

  if (cur > ws_size){
    zero_out_kernel<<<(out_size + 255)/256, 256, 0, stream>>>(d_out, out_size, mode);
    return;
  }
  size_t rem = ws_size - cur;
  long CH_l = (long)((rem / 3) / (512*2)) & ~127L;
  int CH = (int)(CH_l > 8192 ? 8192 : CH_l);
  if (CH < 128){
    zero_out_kernel<<<(out_size + 255)/256, 256, 0, stream>>>(d_out, out_size, mode);
    return;
  }
  u16* bufA = (u16*)alloc((size_t)CH*512*2);
  u16* bufB = (u16*)alloc((size_t)CH*512*2);
  u16* bufC = (u16*)alloc((size_t)CH*512*2);

  auto cvt = [&](const void* src, u16* dst, int n){
    int thr = (n + 7) / 8;
    cvt_kernel<<<(thr + 255)/256, 256, 0, stream>>>(src, dst, n, mode);
  };
  cvt(Wih, wih_b, 2048*256);
  cvt(Whh, whh_b, 2048*512);
  cvt(bih, bih_b, 2048);
  cvt(bhh, bhh_b, 2048);
  cvt(c0,  cbf, BATCH*HDIM);
  cvt(state, st_bf, T_STEPS*BATCH*DDIM);
  cvt(aw0, wa0, 512*768);  cvt(ab0, ba0, 512);
  cvt(aw1, wa1, 512*512);  cvt(ab1, ba1, 512);
  cvt(aw2, wa2, 1536);     cvt(ab2, ba2, 3);
  cvt(cw0, wc0, 512*768);  cvt(cb0, bc0, 512);
  cvt(cw1, wc1, 512*512);  cvt(cb1, bc1, 512);
  cvt(cw2, wc2, 512);      cvt(cb2, bc2, 1);

  hipMemsetAsync(tags, 0, 128*4, stream);
  hipMemsetAsync(probe, 0, 512*4, stream);
  init_h_kernel<<<(BATCH*HDIM/2 + 255)/256, 256, 0, stream>>>(h0, hbuf, mode);
  scan_kernel<<<1, 64, 0, stream>>>(lens, off);
  pack_state_kernel<<<(T_STEPS*BATCH)/4, 256, 0, stream>>>(st_bf, lens, off, inp);

  lstm_kernel<<<128, 512, 0, stream>>>(whh_b, wih_b, bih_b, bhh_b, cbf, st_bf,
                                       hbuf, inp, off, lens, tags, probe);

  for (int cs = 0; cs < Np128; cs += CH){
    int rows = (Np128 - cs) < CH ? (Np128 - cs) : CH;
    int gm = rows / 128;
    dim3 gg(gm, 4);
    gemm_kernel<<<gg, 256, 0, stream>>>(inp + (long)cs*768, wa0, ba0, bufA, 768);
    gemm_kernel<<<gg, 256, 0, stream>>>(bufA,               wa1, ba1, bufB, 512);
    gemm_kernel<<<gg, 256, 0, stream>>>(inp + (long)cs*768, wc0, bc0, bufA, 768);
    gemm_kernel<<<gg, 256, 0, stream>>>(bufA,               wc1, bc1, bufC, 512);
    int nvalid = (N - cs) < rows ? (N - cs) : rows;
    if (nvalid > 0)
      final_kernel<<<(nvalid + 3)/4, 256, 0, stream>>>(bufB, bufC, wa2, ba2,
                                                       wc2, bc2, d_out, cs,
                                                       nvalid, N, mode);
  }
}

// Round 9
// 2322.621 us; speedup vs baseline: 337.8091x; 337.8091x over previous
//
#include <hip/hip_runtime.h>
#include <stdint.h>

// RNNPPO: LSTM(512 steps) + ragged pack + 2x MLP heads. DTYPE-ROBUST (sniff
// fp32-vs-bf16, normalize to bf16, output per mode).
//
// R16: R13/R14/R15 (ack-free sc0 tag-fused polling) = 2 timeouts + one
// 820ms/dispatch wedge (R15: every step burned quick-poll + full backstop,
// absmax drift). Conclusion: sc0 store->poll signaling without the
// drain->barrier->tag ordering is NOT reliable on this part; and R12's
// 1940us implies MALL-class trips, so its win was likely x-dedup + agent
// protocol. R16 = LSTM reverted BYTE-FOR-BYTE to R12 (proven 1940us,
// absmax 0.0039) + the never-touched MLP tail optimized:
//  - 2-phase prefetch GEMM (double-buffered LDS; stage tile t+1 before
//    computing tile t; one vmcnt(0)+barrier per tile). Catalog T3-minimum.
//  - actor/critic layer-0 fused into one [1024x768] stacked-weight GEMM
//    (halves inp reads, one fewer launch); layer-1 reads lda=1024 slices.

#define T_STEPS 512
#define BATCH   128
#define DDIM    256
#define HDIM    512

typedef __attribute__((ext_vector_type(8))) short bf16x8;
typedef __attribute__((ext_vector_type(4))) float f32x4;
typedef __attribute__((ext_vector_type(2))) unsigned long long u64x2;
typedef unsigned short u16;
typedef unsigned int   u32;
typedef unsigned long long u64;
typedef __attribute__((ext_vector_type(4))) u32 u32x4;

__device__ __forceinline__ u16 f2bf(float x){
  u32 u = __builtin_bit_cast(u32, x);
  u32 r = u + 0x7fffu + ((u >> 16) & 1u);
  return (u16)(r >> 16);
}
__device__ __forceinline__ float bf2f(u16 h){
  u32 u = ((u32)h) << 16;
  return __builtin_bit_cast(float, u);
}
__device__ __forceinline__ float sigm(float x){ return 1.f/(1.f + __expf(-x)); }
__device__ __forceinline__ float tanh_f(float x){ return 1.f - 2.f/(1.f + __expf(2.f*x)); }

__device__ __forceinline__ void async_ld16(const void* g, void* l){
  __builtin_amdgcn_global_load_lds(
      (const __attribute__((address_space(1))) u32*)g,
      (__attribute__((address_space(3))) u32*)l, 16, 0, 0);
}

// ---- SE(XCD-L2)-scope ops: sc0 = bypass L1, service at this XCD's L2 ----
__device__ __forceinline__ u32 ld_u32_sc0(const int* p){
  u32 v;
  asm volatile("global_load_dword %0, %1, off sc0\n\t"
               "s_waitcnt vmcnt(0)"
               : "=&v"(v) : "v"(p) : "memory");
  return v;
}
__device__ __forceinline__ void st_u32_sc0(int* p, u32 v){
  asm volatile("global_store_dword %0, %1, off sc0" :: "v"(p), "v"(v) : "memory");
}
__device__ __forceinline__ void ld2_b128_sc0_issue(const void* p0, const void* p1,
                                                   u32x4& A0, u32x4& A1){
  asm volatile("global_load_dwordx4 %0, %2, off sc0\n\t"
               "global_load_dwordx4 %1, %3, off sc0"
               : "=&v"(A0), "=&v"(A1) : "v"(p0), "v"(p1) : "memory");
}
// ---- system-scope issue (agent/slow path) ----
__device__ __forceinline__ void ld2_b128_cc_issue(const void* p0, const void* p1,
                                                  u32x4& A0, u32x4& A1){
  asm volatile("global_load_dwordx4 %0, %2, off sc0 sc1\n\t"
               "global_load_dwordx4 %1, %3, off sc0 sc1"
               : "=&v"(A0), "=&v"(A1) : "v"(p0), "v"(p1) : "memory");
}

// ---------------- dtype sniff ----------------
__global__ void sniff_kernel(const u16* __restrict__ b, int* __restrict__ mode){
  if (threadIdx.x == 0){
    int bad = 0;
    for (int i = 0; i < 64; i++){
      u16 x = b[2*i];
      int e = (x >> 7) & 0xFF;         // bf16 exponent
      if (e < 0x60 || e > 0x85) bad++; // outside ~[2^-31, 2^6]
    }
    *mode = (bad > 16) ? 1 : 0;        // 1 = fp32 inputs, 0 = bf16 inputs
  }
}

// ---------------- convert anything -> bf16 ----------------
__global__ void cvt_kernel(const void* __restrict__ src, u16* __restrict__ dst,
                           int n, const int* __restrict__ mode){
  int i0 = (blockIdx.x*blockDim.x + threadIdx.x) * 8;
  if (i0 >= n) return;
  int m = *mode;
  if (m){
    const float* s = (const float*)src;
    if (i0 + 8 <= n){
      float4 a = *(const float4*)(s + i0);
      float4 b = *(const float4*)(s + i0 + 4);
      ushort4 oa, ob;
      oa.x=f2bf(a.x); oa.y=f2bf(a.y); oa.z=f2bf(a.z); oa.w=f2bf(a.w);
      ob.x=f2bf(b.x); ob.y=f2bf(b.y); ob.z=f2bf(b.z); ob.w=f2bf(b.w);
      *(ushort4*)(dst + i0) = oa;
      *(ushort4*)(dst + i0 + 4) = ob;
    } else {
      for (int i = i0; i < n; i++) dst[i] = f2bf(s[i]);
    }
  } else {
    const u16* s = (const u16*)src;
    if (i0 + 8 <= n){
      *(ushort4*)(dst + i0)     = *(const ushort4*)(s + i0);
      *(ushort4*)(dst + i0 + 4) = *(const ushort4*)(s + i0 + 4);
    } else {
      for (int i = i0; i < n; i++) dst[i] = s[i];
    }
  }
}

// ---------------- prep ----------------
__global__ void scan_kernel(const int* __restrict__ lens, int* __restrict__ off){
  if (threadIdx.x == 0){
    int a = 0;
    for (int b = 0; b < BATCH; b++){ off[b] = a; a += lens[b]; }
    off[BATCH] = a;
  }
}

__global__ void pack_state_kernel(const u16* __restrict__ st_bf,
                                  const int* __restrict__ lens,
                                  const int* __restrict__ off,
                                  u16* __restrict__ inp){
  int r = blockIdx.x*4 + (threadIdx.x >> 6);   // dense row t*BATCH+b
  int lane = threadIdx.x & 63;
  int b = r & (BATCH-1), t = r >> 7;
  if (t >= lens[b]) return;
  long row = (long)off[b] + t;
  ushort4 v = ((const ushort4*)(st_bf + (long)r*DDIM))[lane];
  ((ushort4*)(inp + row*768))[lane] = v;
}

__global__ void zero_out_kernel(void* __restrict__ out, int n,
                                const int* __restrict__ mode){
  int i = blockIdx.x*blockDim.x + threadIdx.x;
  if (i >= n) return;
  if (*mode) ((float*)out)[i] = 0.f; else ((u16*)out)[i] = 0;
}

// ---------------- LSTM recurrence (VERBATIM R12 -- proven 1940us) --------
__global__ __launch_bounds__(512, 1) void lstm_kernel(
    const u16* __restrict__ Whh, const u16* __restrict__ Wih,
    const u16* __restrict__ bih, const u16* __restrict__ bhh,
    const u16* __restrict__ cell0,
    const u16* __restrict__ state,
    u16* hbuf,                              // [2][BATCH*HDIM]
    u16* __restrict__ inp,                  // [Np128*768]
    const int* __restrict__ off, const int* __restrict__ lens,
    int* tags,                              // [8*16] per-(g,s) step tags
    int* probe)                             // [128 sig][128 ptag][bad][cnt]
{
  const int tid  = threadIdx.x;
  const int wave = tid >> 6;
  const int lane = tid & 63;
  const int g    = blockIdx.x & 7;      // batch group == XCD (round-robin)
  const int s    = blockIdx.x >> 3;     // col-WG 0..15 (32 h-cols each)
  const int Sb   = s * 32;
  const int q    = lane >> 4;
  const int m16  = lane & 15;

  __shared__ u16  wlds[65536];          // 128 KB
  __shared__ u16  hlds[8192];           // 16 KB
  __shared__ float lds_acc[8][16][16];  // 8 KB
  __shared__ float bias_l[128];
  __shared__ int   len_l[16];
  __shared__ int   off_l[16];
  __shared__ int   fast_l;

  // -------- preflight: sc0 same-XCD visibility probe + global consensus ---
  if (wave == 0){
    if (lane == 0){
      st_u32_sc0(&probe[blockIdx.x], 0xC0FFEE00u | (u32)blockIdx.x);
      asm volatile("s_waitcnt vmcnt(0)" ::: "memory");
      st_u32_sc0(&probe[128 + blockIdx.x], 1u);
    }
    int seen = 1;
    if (lane < 16){
      int partner = 8*lane + g;         // the 16 WGs of group g
      seen = 0;
      for (int sp = 0; sp < (1 << 11); sp++){
        u32 tgv = ld_u32_sc0(&probe[128 + partner]);
        if (tgv == 1u){
          u32 v = ld_u32_sc0(&probe[partner]);
          if (v == (0xC0FFEE00u | (u32)partner)) seen = 1;
          break;                        // tag seen: sig must match NOW
        }
      }
    }
    int okl = __all(seen != 0) ? 1 : 0;
    if (lane == 0){
      if (!okl)
        __hip_atomic_fetch_or(&probe[256], 1,
                              __ATOMIC_RELAXED, __HIP_MEMORY_SCOPE_AGENT);
      __hip_atomic_fetch_add(&probe[257], 1,
                             __ATOMIC_RELEASE, __HIP_MEMORY_SCOPE_AGENT);
      int sp2 = 0;
      while (__hip_atomic_load(&probe[257], __ATOMIC_ACQUIRE,
                               __HIP_MEMORY_SCOPE_AGENT) < 128){
        if (++sp2 >= (1 << 16)) break;
      }
      int bad = __hip_atomic_load(&probe[256], __ATOMIC_RELAXED,
                                  __HIP_MEMORY_SCOPE_AGENT);
      int cnt = __hip_atomic_load(&probe[257], __ATOMIC_RELAXED,
                                  __HIP_MEMORY_SCOPE_AGENT);
      fast_l = (!bad && cnt >= 128) ? 1 : 0;
    }
  }

  if (tid < 128){
    int gt = tid >> 5, jx = tid & 31;
    int cg = gt*HDIM + Sb + jx;
    bias_l[tid] = bf2f(bih[cg]) + bf2f(bhh[cg]);
  }
  if (tid < 16){ len_l[tid] = lens[g*16 + tid]; off_l[tid] = off[g*16 + tid]; }

  // one-time: stage Whh slice into LDS, frag order:
  // chunk ch = (w*16 + c)*64 + l  holds  W[col(w, l&15)][c*32 + (l>>4)*8 ..+8]
  for (int i = 0; i < 16; i++){
    int ch = tid + 512*i;               // 0..8191
    int w = ch >> 10;
    int rem = ch & 1023;
    int c = rem >> 6;
    int l = rem & 63;
    int col = (w >> 1)*HDIM + Sb + (w & 1)*16 + (l & 15);
    int k = c*32 + (l >> 4)*8;
    u64x2 v = *(const u64x2*)(Whh + (long)col*HDIM + k);
    *(u64x2*)(&wlds[(size_t)ch*8]) = v;
  }

  // Wih fragments in VGPRs
  const int gate = wave >> 1;
  const int hf   = wave & 1;
  const int colg = gate*HDIM + Sb + hf*16 + m16;
  bf16x8 wih[8];
  {
    const u16* wb2 = Wih + (long)colg*DDIM + q*8;
    #pragma unroll
    for (int c = 0; c < 8; c++) wih[c] = *(const bf16x8*)(wb2 + c*32);
  }

  const int b_l = tid >> 5;    // epilogue ownership: (batch b_l, col j)
  const int j   = tid & 31;
  const int hx  = j >> 4;
  const int jj  = j & 15;
  float cval = bf2f(cell0[(g*16 + b_l)*HDIM + Sb + j]);

  // consumer co-op chunk assignment (2 chunks/thread, conflict-free writes)
  const int m0 = tid, m1 = tid + 512;
  const int c0i = m0 >> 6, c1i = m1 >> 6;
  const int r0 = m0 & 15;                 // == m1 & 15
  const int k0 = c0i*32 + ((m0 & 63) >> 4)*8;
  const int k1 = c1i*32 + ((m1 & 63) >> 4)*8;

  int* tg = tags + g*16;

  __syncthreads();
  const int fast = fast_l;

  for (int t = 0; t < T_STEPS; t++){
    f32x4 acc  = {0.f, 0.f, 0.f, 0.f};
    f32x4 acc2 = {0.f, 0.f, 0.f, 0.f};
    // A: x loads issue (plain cached; group co-XCD -> L2-hit after 1st WG)
    bf16x8 xa[8];
    {
      const u16* xb = state + ((long)(t*BATCH + g*16 + m16))*DDIM + q*8;
      #pragma unroll
      for (int c = 0; c < 8; c++) xa[c] = *(const bf16x8*)(xb + c*32);
    }
    // B: cheap detect -- each wave polls the group's single 64B tag line.
    if (t > 0){
      int spins = 0;
      if (fast){
        for (;;){
          int tv = 0x7fffffff;
          if (lane < 16) tv = (int)ld_u32_sc0(&tg[lane]);
          if (__all(tv >= t)) break;
          if (++spins > (1 << 14)) break;  // wedge -> wrong answer, not hang
        }
      } else {
        for (;;){
          int tv = 0x7fffffff;
          if (lane < 16)
            tv = __hip_atomic_load(&tg[lane], __ATOMIC_RELAXED,
                                   __HIP_MEMORY_SCOPE_AGENT);
          if (__all(tv >= t)) break;
          if (++spins > (1 << 14)) break;
        }
      }
      asm volatile("" ::: "memory");     // no hoisting h loads above poll
    }
    // C: one-shot bulk h read; x-MFMAs overlap the load flight
    const u16* hp = hbuf + ((t & 1) ^ 1)*(BATCH*HDIM) + (size_t)g*16*HDIM;
    u32x4 A0, A1;
    if (fast) ld2_b128_sc0_issue(hp + r0*HDIM + k0, hp + r0*HDIM + k1, A0, A1);
    else      ld2_b128_cc_issue (hp + r0*HDIM + k0, hp + r0*HDIM + k1, A0, A1);
    #pragma unroll
    for (int c = 0; c < 8; c++)
      acc = __builtin_amdgcn_mfma_f32_16x16x32_bf16(xa[c], wih[c], acc, 0, 0, 0);
    asm volatile("s_waitcnt vmcnt(0)" ::: "memory");
    __builtin_amdgcn_sched_barrier(0);
    *(u32x4*)(&hlds[(size_t)m0*8]) = A0;
    *(u32x4*)(&hlds[(size_t)m1*8]) = A1;
    __syncthreads();                   // barrier 1: hlds ready
    // E: h MFMAs, weights from LDS (two interleaved chains)
    #pragma unroll
    for (int cc = 0; cc < 8; cc++){
      bf16x8 a0 = *(const bf16x8*)(&hlds[(size_t)((2*cc    )*64 + lane)*8]);
      bf16x8 a1 = *(const bf16x8*)(&hlds[(size_t)((2*cc + 1)*64 + lane)*8]);
      bf16x8 w0 = *(const bf16x8*)(&wlds[(size_t)((wave*16 + 2*cc    )*64 + lane)*8]);
      bf16x8 w1 = *(const bf16x8*)(&wlds[(size_t)((wave*16 + 2*cc + 1)*64 + lane)*8]);
      acc  = __builtin_amdgcn_mfma_f32_16x16x32_bf16(a0, w0, acc,  0, 0, 0);
      acc2 = __builtin_amdgcn_mfma_f32_16x16x32_bf16(a1, w1, acc2, 0, 0, 0);
    }
    // F: gate exchange through LDS (C layout: row(batch)=q*4+r, col=m16)
    #pragma unroll
    for (int r = 0; r < 4; r++)
      lds_acc[wave][q*4 + r][m16] = acc[r] + acc2[r];
    __syncthreads();                   // barrier 2: gates ready

    // G: epilogue + release: h stores -> per-wave ack -> WG barrier (all
    // waves acked) -> single tag store.
    float iv = lds_acc[0 + hx][b_l][jj] + bias_l[ 0 + j];
    float fv = lds_acc[2 + hx][b_l][jj] + bias_l[32 + j];
    float gv = lds_acc[4 + hx][b_l][jj] + bias_l[64 + j];
    float ov = lds_acc[6 + hx][b_l][jj] + bias_l[96 + j];
    cval = sigm(fv)*cval + sigm(iv)*tanh_f(gv);
    float hv = sigm(ov)*tanh_f(cval);
    u16 hb16 = f2bf(hv);
    int nb = __shfl_down((int)hb16, 1);
    if ((j & 1) == 0){
      size_t hidx = (size_t)(t & 1)*(BATCH*HDIM) + (g*16 + b_l)*HDIM + Sb + j;
      u32 pair = (u32)hb16 | ((u32)(u16)nb << 16);
      if (fast) st_u32_sc0((int*)(hbuf + hidx), pair);
      else      __hip_atomic_store((u32*)(hbuf + hidx), pair,
                                   __ATOMIC_RELAXED, __HIP_MEMORY_SCOPE_AGENT);
    }
    __builtin_amdgcn_s_waitcnt(0);     // own wave's h stores ack'd at scope
    __syncthreads();                   // barrier 3: every wave's stores ack'd
    if (tid == 0){
      if (fast) st_u32_sc0(&tg[s], (u32)(t + 1));
      else      __hip_atomic_store(&tg[s], t + 1,
                                   __ATOMIC_RELAXED, __HIP_MEMORY_SCOPE_AGENT);
    }
    // packed-h store fully off the release path
    if (t < len_l[b_l])
      inp[((long)(off_l[b_l] + t))*768 + DDIM + Sb + j] = hb16;
  }
}

// ---------------- MLP GEMM: C = relu(A @ W^T + bias), bf16 in/out ---------
// 2-phase prefetch (double-buffered LDS; stage t+1 before compute t).
// lda/ldc in elements; W is [outcols x K] row-major.
__global__ __launch_bounds__(256) void gemm_kernel(
    const u16* __restrict__ A, int lda,
    const u16* __restrict__ W,
    const u16* __restrict__ bias,
    u16* __restrict__ C, int ldc,
    int K)
{
  __shared__ u16 As[2][128*32];
  __shared__ u16 Bs[2][128*32];
  const int tid = threadIdx.x, wave = tid >> 6, lane = tid & 63;
  const int bm = blockIdx.x * 128;
  const int bn = blockIdx.y * 128;
  const int wr = (wave >> 1) * 64;
  const int wc = (wave & 1) * 64;
  const int q = lane >> 4, m16 = lane & 15;
  const int rsub = lane >> 2;          // 0..15
  const int ksub = (lane & 3) * 8;     // elems

  f32x4 acc[4][4] = {};
  const int nt = K >> 5;               // K multiple of 32

  // prologue: stage tile 0 into buffer 0
  #pragma unroll
  for (int i = 0; i < 2; i++){
    int rr = (i*4 + wave) * 16 + rsub;
    async_ld16(A + (long)(bm + rr)*lda + ksub, As[0] + (i*4 + wave)*512);
    async_ld16(W + (long)(bn + rr)*K   + ksub, Bs[0] + (i*4 + wave)*512);
  }
  asm volatile("s_waitcnt vmcnt(0)" ::: "memory");
  __syncthreads();

  for (int t = 0; t < nt; t++){
    const int cur = t & 1;
    // stage next tile into the other buffer (in flight during compute)
    if (t + 1 < nt){
      int kk = (t + 1) << 5;
      #pragma unroll
      for (int i = 0; i < 2; i++){
        int rr = (i*4 + wave) * 16 + rsub;
        async_ld16(A + (long)(bm + rr)*lda + kk + ksub, As[cur ^ 1] + (i*4 + wave)*512);
        async_ld16(W + (long)(bn + rr)*K   + kk + ksub, Bs[cur ^ 1] + (i*4 + wave)*512);
      }
    }
    bf16x8 af[4], bfr[4];
    #pragma unroll
    for (int r = 0; r < 4; r++) af[r]  = *(const bf16x8*)(As[cur] + (wr + r*16 + m16)*32 + q*8);
    #pragma unroll
    for (int c = 0; c < 4; c++) bfr[c] = *(const bf16x8*)(Bs[cur] + (wc + c*16 + m16)*32 + q*8);
    #pragma unroll
    for (int r = 0; r < 4; r++)
      #pragma unroll
      for (int c = 0; c < 4; c++)
        acc[r][c] = __builtin_amdgcn_mfma_f32_16x16x32_bf16(af[r], bfr[c], acc[r][c], 0, 0, 0);
    asm volatile("s_waitcnt vmcnt(0)" ::: "memory");
    __syncthreads();                   // next buffer ready for all waves
  }
  #pragma unroll
  for (int c = 0; c < 4; c++){
    int col = bn + wc + c*16 + m16;
    float bv = bf2f(bias[col]);
    #pragma unroll
    for (int r = 0; r < 4; r++){
      #pragma unroll
      for (int x = 0; x < 4; x++){
        int row = bm + wr + r*16 + q*4 + x;
        float v = acc[r][c][x] + bv;
        v = fmaxf(v, 0.f);
        C[(long)row*ldc + col] = f2bf(v);
      }
    }
  }
}

// ---------------- final fused layer: actor(3, tanh) + critic(1) ----------------
__global__ void final_kernel(
    const u16* __restrict__ a2, const u16* __restrict__ c2,
    const u16* __restrict__ aw2, const u16* __restrict__ ab2,
    const u16* __restrict__ cw2, const u16* __restrict__ cb2,
    void* __restrict__ out, int base, int nvalid, int N,
    const int* __restrict__ mode)
{
  int lw = (blockIdx.x * blockDim.x + threadIdx.x) >> 6;   // local row
  int lane = threadIdx.x & 63;
  if (lw >= nvalid) return;
  int k = lane * 8;
  bf16x8 av = *(const bf16x8*)(a2 + (long)lw*512 + k);
  bf16x8 cv = *(const bf16x8*)(c2 + (long)lw*512 + k);
  bf16x8 w0 = *(const bf16x8*)(aw2 + k);
  bf16x8 w1 = *(const bf16x8*)(aw2 + 512 + k);
  bf16x8 w2 = *(const bf16x8*)(aw2 + 1024 + k);
  bf16x8 wc = *(const bf16x8*)(cw2 + k);
  float d0=0.f, d1=0.f, d2=0.f, dc=0.f;
  #pragma unroll
  for (int x = 0; x < 8; x++){
    float a  = bf2f((u16)av[x]);
    float cc = bf2f((u16)cv[x]);
    d0 += a  * bf2f((u16)w0[x]);
    d1 += a  * bf2f((u16)w1[x]);
    d2 += a  * bf2f((u16)w2[x]);
    dc += cc * bf2f((u16)wc[x]);
  }
  #pragma unroll
  for (int o = 32; o > 0; o >>= 1){
    d0 += __shfl_down(d0, o);
    d1 += __shfl_down(d1, o);
    d2 += __shfl_down(d2, o);
    dc += __shfl_down(dc, o);
  }
  if (lane == 0){
    int gr = base + lw;
    float r0 = tanh_f(d0 + bf2f(ab2[0]));
    float r1 = tanh_f(d1 + bf2f(ab2[1]));
    float r2 = tanh_f(d2 + bf2f(ab2[2]));
    float rc = dc + bf2f(cb2[0]);
    if (*mode){
      float* o = (float*)out;
      o[(long)gr*3 + 0] = r0; o[(long)gr*3 + 1] = r1; o[(long)gr*3 + 2] = r2;
      o[(long)3*N + gr] = rc;
    } else {
      u16* o = (u16*)out;
      o[(long)gr*3 + 0] = f2bf(r0); o[(long)gr*3 + 1] = f2bf(r1);
      o[(long)gr*3 + 2] = f2bf(r2);
      o[(long)3*N + gr] = f2bf(rc);
    }
  }
}

extern "C" void kernel_launch(void* const* d_in, const int* in_sizes, int n_in,
                              void* d_out, int out_size, void* d_ws, size_t ws_size,
                              hipStream_t stream)
{
  const void* state = d_in[0];
  const void* h0    = d_in[1];
  const void* c0    = d_in[2];
  const int*  lens  = (const int*)d_in[3];
  const void* Wih   = d_in[4];
  const void* Whh   = d_in[5];
  const void* bih   = d_in[6];
  const void* bhh   = d_in[7];
  const void* aw0   = d_in[8];
  const void* ab0   = d_in[9];
  const void* aw1   = d_in[10];
  const void* ab1   = d_in[11];
  const void* aw2   = d_in[12];
  const void* ab2   = d_in[13];
  const void* cw0   = d_in[14];
  const void* cb0   = d_in[15];
  const void* cw1   = d_in[16];
  const void* cb1   = d_in[17];
  const void* cw2   = d_in[18];
  const void* cb2   = d_in[19];
  (void)in_sizes; (void)n_in;

  const int N = out_size / 4;             // actor 3N + critic N
  const int Np128 = (N + 127) & ~127;

  char* ws = (char*)d_ws;
  size_t cur = 0;
  auto alloc = [&](size_t bytes)->char*{
    char* p = ws + cur; cur += (bytes + 255) & ~(size_t)255; return p;
  };
  int* mode   = (int*)alloc(4);
  int* off    = (int*)alloc(129*4);
  int* tags   = (int*)alloc(128*4);
  int* probe  = (int*)alloc(512*4);
  u16* hbuf   = (u16*)alloc((size_t)2*BATCH*HDIM*2);
  u16* cbf    = (u16*)alloc((size_t)BATCH*HDIM*2);
  u16* wih_b  = (u16*)alloc((size_t)2048*256*2);
  u16* whh_b  = (u16*)alloc((size_t)2048*512*2);
  u16* bih_b  = (u16*)alloc(2048*2);
  u16* bhh_b  = (u16*)alloc(2048*2);
  u16* st_bf  = (u16*)alloc((size_t)T_STEPS*BATCH*DDIM*2);
  u16* wst0   = (u16*)alloc((size_t)1024*768*2);   // [wa0 ; cw0] stacked
  u16* bst0   = (u16*)alloc(1024*2);               // [ab0 ; cb0]
  u16* wa1    = (u16*)alloc((size_t)512*512*2);
  u16* ba1    = (u16*)alloc(512*2);
  u16* wa2    = (u16*)alloc(1536*2);
  u16* ba2    = (u16*)alloc(256*2);
  u16* wc1    = (u16*)alloc((size_t)512*512*2);
  u16* bc1    = (u16*)alloc(512*2);
  u16* wc2    = (u16*)alloc(512*2);
  u16* bc2    = (u16*)alloc(256*2);
  u16* inp    = (u16*)alloc((size_t)Np128*768*2);

  sniff_kernel<<<1, 64, 0, stream>>>((const u16*)bih, mode);

  if (cur > ws_size){
    zero_out_kernel<<<(out_size + 255)/256, 256, 0, stream>>>(d_out, out_size, mode);
    return;
  }
  size_t rem = ws_size - cur;
  // bufA: CH x 1024 (stacked L0 out), bufB/bufC: CH x 512 each
  long CH_l = (long)(rem / (2048*2)) & ~127L;
  int CH = (int)(CH_l > 8192 ? 8192 : CH_l);
  if (CH < 128){
    zero_out_kernel<<<(out_size + 255)/256, 256, 0, stream>>>(d_out, out_size, mode);
    return;
  }
  u16* bufA = (u16*)alloc((size_t)CH*1024*2);
  u16* bufB = (u16*)alloc((size_t)CH*512*2);
  u16* bufC = (u16*)alloc((size_t)CH*512*2);

  auto cvt = [&](const void* src, u16* dst, int n){
    int thr = (n + 7) / 8;
    cvt_kernel<<<(thr + 255)/256, 256, 0, stream>>>(src, dst, n, mode);
  };
  cvt(Wih, wih_b, 2048*256);
  cvt(Whh, whh_b, 2048*512);
  cvt(bih, bih_b, 2048);
  cvt(bhh, bhh_b, 2048);
  cvt(h0,  hbuf + BATCH*HDIM, BATCH*HDIM);   // parity 1 = h_{-1}
  cvt(c0,  cbf, BATCH*HDIM);
  cvt(state, st_bf, T_STEPS*BATCH*DDIM);
  cvt(aw0, wst0, 512*768);
  cvt(cw0, wst0 + (size_t)512*768, 512*768);
  cvt(ab0, bst0, 512);
  cvt(cb0, bst0 + 512, 512);
  cvt(aw1, wa1, 512*512);  cvt(ab1, ba1, 512);
  cvt(aw2, wa2, 1536);     cvt(ab2, ba2, 3);
  cvt(cw1, wc1, 512*512);  cvt(cb1, bc1, 512);
  cvt(cw2, wc2, 512);      cvt(cb2, bc2, 1);

  hipMemsetAsync(tags, 0, 128*4, stream);
  hipMemsetAsync(probe, 0, 512*4, stream);
  scan_kernel<<<1, 64, 0, stream>>>(lens, off);
  pack_state_kernel<<<(T_STEPS*BATCH)/4, 256, 0, stream>>>(st_bf, lens, off, inp);

  lstm_kernel<<<128, 512, 0, stream>>>(whh_b, wih_b, bih_b, bhh_b, cbf, st_bf,
                                       hbuf, inp, off, lens, tags, probe);

  for (int cs = 0; cs < Np128; cs += CH){
    int rows = (Np128 - cs) < CH ? (Np128 - cs) : CH;
    int gm = rows / 128;
    // fused L0: [actor|critic] = relu(inp @ wst0^T + bst0), 1024 cols
    gemm_kernel<<<dim3(gm, 8), 256, 0, stream>>>(inp + (long)cs*768, 768,
                                                 wst0, bst0, bufA, 1024, 768);
    // L1 actor: reads cols 0..511 of bufA (lda=1024)
    gemm_kernel<<<dim3(gm, 4), 256, 0, stream>>>(bufA, 1024,
                                                 wa1, ba1, bufB, 512, 512);
    // L1 critic: reads cols 512..1023 of bufA
    gemm_kernel<<<dim3(gm, 4), 256, 0, stream>>>(bufA + 512, 1024,
                                                 wc1, bc1, bufC, 512, 512);
    int nvalid = (N - cs) < rows ? (N - cs) : rows;
    if (nvalid > 0)
      final_kernel<<<(nvalid + 3)/4, 256, 0, stream>>>(bufB, bufC, wa2, ba2,
                                                       wc2, bc2, d_out, cs,
                                                       nvalid, N, mode);
  }
}